// Round 3
// baseline (3220.619 us; speedup 1.0000x reference)
//
#include <hip/hip_runtime.h>
#include <hip/hip_bf16.h>

#define NPTS 262144
#define NJ   24
#define NC   16
#define NG   128

// One thread per (n,j) pair, scalar f32, raw input layouts, f32 OUTPUT.
__global__ __launch_bounds__(256) void simple_trisample_k(
    const float* __restrict__ xyz, const float* __restrict__ Tm,
    const float* __restrict__ p0, const float* __restrict__ p1,
    const float* __restrict__ p2, const float* __restrict__ l0,
    const float* __restrict__ l1, const float* __restrict__ l2,
    float* __restrict__ out)
{
    const int tid = blockIdx.x * 256 + threadIdx.x;   // [0, NPTS*NJ)
    const int j = tid >> 18;          // NPTS = 2^18, j-major for L2 locality
    const int n = tid & (NPTS - 1);

    const float x = xyz[3*n+0], y = xyz[3*n+1], z = xyz[3*n+2];
    const float* Tj = Tm + 16*j;

    // pts[a] = sum_b T[j,a,b] * [x,y,z,1][b];  g = (pts + 1.5) * (2/3) - 1
    float g[3];
#pragma unroll
    for (int a = 0; a < 3; ++a) {
        const float pt = Tj[4*a+0]*x + Tj[4*a+1]*y + Tj[4*a+2]*z + Tj[4*a+3];
        g[a] = (pt + 1.5f) * (2.0f/3.0f) - 1.0f;
    }

    const float* P[3] = {p0, p1, p2};
    const float* L[3] = {l0, l1, l2};
    const int M0[3] = {0,0,1}, M1[3] = {1,2,2}, MV[3] = {2,1,0};

    float sigma = 0.0f;
#pragma unroll
    for (int p = 0; p < 3; ++p) {
        const float gx = g[M0[p]];   // -> x index (last dim, W)
        const float gy = g[M1[p]];   // -> y index (H)
        const float gz = g[MV[p]];   // -> line index (L)

        const float ix = (gx + 1.0f) * 0.5f * (NG - 1);
        const float iy = (gy + 1.0f) * 0.5f * (NG - 1);
        const float iz = (gz + 1.0f) * 0.5f * (NG - 1);
        const float fx = floorf(ix), fy = floorf(iy), fz = floorf(iz);
        const int x0 = (int)fx, y0 = (int)fy, z0 = (int)fz;
        const float wx1 = ix - fx, wy1 = iy - fy, wz1 = iz - fz;

        // zero-padding validity folded into per-axis weights
        const float mx0 = (x0   >= 0 && x0   < NG) ? (1.0f - wx1) : 0.0f;
        const float mx1 = (x0+1 >= 0 && x0+1 < NG) ? wx1 : 0.0f;
        const float my0 = (y0   >= 0 && y0   < NG) ? (1.0f - wy1) : 0.0f;
        const float my1 = (y0+1 >= 0 && y0+1 < NG) ? wy1 : 0.0f;
        const float mz0 = (z0   >= 0 && z0   < NG) ? (1.0f - wz1) : 0.0f;
        const float mz1 = (z0+1 >= 0 && z0+1 < NG) ? wz1 : 0.0f;

        const int xc0 = min(max(x0,   0), NG-1), xc1 = min(max(x0+1, 0), NG-1);
        const int yc0 = min(max(y0,   0), NG-1), yc1 = min(max(y0+1, 0), NG-1);
        const int zc0 = min(max(z0,   0), NG-1), zc1 = min(max(z0+1, 0), NG-1);

        const float w00 = mx0*my0, w01 = mx1*my0, w10 = mx0*my1, w11 = mx1*my1;
        const int o00 = yc0*NG + xc0, o01 = yc0*NG + xc1;
        const int o10 = yc1*NG + xc0, o11 = yc1*NG + xc1;

        const float* pb = P[p] + (size_t)j * NC * NG * NG;   // [C][G][G]
        const float* lb = L[p] + (size_t)j * NC * NG;        // [C][G]

#pragma unroll 4
        for (int c = 0; c < NC; ++c) {
            const float* pc = pb + (size_t)c * NG * NG;
            const float pf = pc[o00]*w00 + pc[o01]*w01 + pc[o10]*w10 + pc[o11]*w11;
            const float* lc = lb + (size_t)c * NG;
            const float lf = lc[zc0]*mz0 + lc[zc1]*mz1;
            sigma += pf * lf;
        }
    }

    out[(size_t)n * NJ + j] = fmaxf(sigma, 0.0f);   // f32 output
}

extern "C" void kernel_launch(void* const* d_in, const int* in_sizes, int n_in,
                              void* d_out, int out_size, void* d_ws, size_t ws_size,
                              hipStream_t stream) {
    // Identify inputs by flat element count (robust to harness ordering);
    // relative order within equal-size groups (planes, lines) is preserved.
    const float* xyz = nullptr;
    const float* Tm  = nullptr;
    const float* P[3] = {nullptr, nullptr, nullptr};
    const float* L[3] = {nullptr, nullptr, nullptr};
    int pi = 0, li = 0;
    for (int i = 0; i < n_in; ++i) {
        const int s = in_sizes[i];
        if      (s == NPTS * 3)            xyz = (const float*)d_in[i];
        else if (s == 16 * NJ)             Tm  = (const float*)d_in[i];
        else if (s == NJ * NC * NG * NG) { if (pi < 3) P[pi++] = (const float*)d_in[i]; }
        else if (s == NJ * NC * NG)      { if (li < 3) L[li++] = (const float*)d_in[i]; }
    }
    if (!xyz || !Tm || pi != 3 || li != 3) {   // fallback: documented dict order
        xyz = (const float*)d_in[0];  Tm = (const float*)d_in[1];
        P[0] = (const float*)d_in[2]; P[1] = (const float*)d_in[3];
        P[2] = (const float*)d_in[4];
        L[0] = (const float*)d_in[5]; L[1] = (const float*)d_in[6];
        L[2] = (const float*)d_in[7];
    }
    float* out = (float*)d_out;

    const int nblocks = (NPTS * NJ) / 256;    // 24576, exact
    simple_trisample_k<<<nblocks, 256, 0, stream>>>(xyz, Tm, P[0], P[1], P[2],
                                                    L[0], L[1], L[2], out);
}

// Round 4
// 392.440 us; speedup vs baseline: 8.2067x; 8.2067x over previous
//
#include <hip/hip_runtime.h>
#include <hip/hip_bf16.h>

#define NPTS 262144
#define NJ   24
#define NC   16
#define NG   128
#define PSZ  (NJ*NG*NG*NC)   // 6291456 floats per transposed plane
#define LSZ  (NJ*NG*NC)      // 49152 floats per transposed line

// ---------------- transpose pre-passes: [J][C][G][G] -> [J][G][G][C] ----------------
// Thread mapping: c innermost -> writes fully coalesced; reads 4x-amplified
// (16 lanes stride 64KB) but only 75MB total, absorbed by L2/L3.

__global__ __launch_bounds__(256) void transpose_planes_k(
    const float* __restrict__ p0, const float* __restrict__ p1,
    const float* __restrict__ p2, float* __restrict__ ws)
{
    const int p = blockIdx.z, j = blockIdx.y;
    const int idx = blockIdx.x * 256 + threadIdx.x;  // [0, NG*NG*NC)
    const int c = idx & 15;
    const int x = (idx >> 4) & 127;
    const int y = idx >> 11;
    const float* src = (p == 0) ? p0 : (p == 1) ? p1 : p2;
    const float v = src[((j * NC + c) * NG + y) * NG + x];
    ws[(size_t)p * PSZ + (size_t)((j * NG + y) * NG + x) * NC + c] = v;
}

__global__ __launch_bounds__(256) void transpose_lines_k(
    const float* __restrict__ l0, const float* __restrict__ l1,
    const float* __restrict__ l2, float* __restrict__ ws)
{
    const int p = blockIdx.z;
    const int idx = blockIdx.x * 256 + threadIdx.x;  // [0, NJ*NG*NC)
    const int c = idx & 15;
    const int z = (idx >> 4) & 127;
    const int j = idx >> 11;
    const float* src = (p == 0) ? l0 : (p == 1) ? l1 : l2;
    const float v = src[(j * NC + c) * NG + z];
    ws[(size_t)3 * PSZ + (size_t)p * LSZ + (size_t)(j * NG + z) * NC + c] = v;
}

// ---------------- main kernel: 4 lanes per (n,j) pair, 4 channels/lane ----------------

__device__ __forceinline__ float4 f4axpy(const float4 v, const float w, float4 acc) {
    acc.x = fmaf(v.x, w, acc.x);
    acc.y = fmaf(v.y, w, acc.y);
    acc.z = fmaf(v.z, w, acc.z);
    acc.w = fmaf(v.w, w, acc.w);
    return acc;
}

template<bool TR>
__global__ __launch_bounds__(256) void trisample_k(
    const float* __restrict__ xyz, const float* __restrict__ Tm,
    const float* __restrict__ p0, const float* __restrict__ p1,
    const float* __restrict__ p2, const float* __restrict__ l0,
    const float* __restrict__ l1, const float* __restrict__ l2,
    const float* __restrict__ ws, float* __restrict__ out)
{
    const int tid  = blockIdx.x * 256 + threadIdx.x;
    const int quad = tid >> 2;          // pair id, j-major: quad = j*NPTS + n
    const int lc   = (tid & 3) << 2;    // first channel of this lane
    const int j    = quad >> 18;        // NPTS = 2^18
    const int n    = quad & (NPTS - 1);

    const float x = xyz[3*n+0], y = xyz[3*n+1], z = xyz[3*n+2];
    const float* Tj = Tm + 16*j;        // j uniform within block -> scalar loads
    float g[3];
#pragma unroll
    for (int a = 0; a < 3; ++a) {
        const float pt = Tj[4*a+0]*x + Tj[4*a+1]*y + Tj[4*a+2]*z + Tj[4*a+3];
        g[a] = (pt + 1.5f) * (2.0f/3.0f) - 1.0f;   // normalize_coord
    }

    const float* praw[3] = {p0, p1, p2};
    const float* lraw[3] = {l0, l1, l2};
    const int M0[3] = {0,0,1}, M1[3] = {1,2,2}, MV[3] = {2,1,0};

    float4 sig = make_float4(0.f, 0.f, 0.f, 0.f);
#pragma unroll
    for (int p = 0; p < 3; ++p) {
        const float gx = g[M0[p]], gy = g[M1[p]], gz = g[MV[p]];
        const float ix = (gx + 1.f) * 63.5f;     // (g+1)*0.5*(G-1)
        const float iy = (gy + 1.f) * 63.5f;
        const float iz = (gz + 1.f) * 63.5f;
        const float fx = floorf(ix), fy = floorf(iy), fz = floorf(iz);
        const int x0 = (int)fx, y0 = (int)fy, z0 = (int)fz;
        const float wx1 = ix - fx, wy1 = iy - fy, wz1 = iz - fz;
        // zero-padding: fold per-corner validity into per-axis masked weights
        const float mx0 = (x0   >= 0 && x0   < NG) ? (1.f - wx1) : 0.f;
        const float mx1 = (x0+1 >= 0 && x0+1 < NG) ? wx1 : 0.f;
        const float my0 = (y0   >= 0 && y0   < NG) ? (1.f - wy1) : 0.f;
        const float my1 = (y0+1 >= 0 && y0+1 < NG) ? wy1 : 0.f;
        const float mz0 = (z0   >= 0 && z0   < NG) ? (1.f - wz1) : 0.f;
        const float mz1 = (z0+1 >= 0 && z0+1 < NG) ? wz1 : 0.f;
        const int xc0 = min(max(x0,   0), NG-1), xc1 = min(max(x0+1, 0), NG-1);
        const int yc0 = min(max(y0,   0), NG-1), yc1 = min(max(y0+1, 0), NG-1);
        const int zc0 = min(max(z0,   0), NG-1), zc1 = min(max(z0+1, 0), NG-1);

        float4 v00, v01, v10, v11, u0, u1;
        if (TR) {
            const float* pb = ws + (size_t)p * PSZ + (size_t)j * (NG*NG*NC) + lc;
            v00 = *(const float4*)(pb + (yc0*NG + xc0)*NC);
            v01 = *(const float4*)(pb + (yc0*NG + xc1)*NC);
            v10 = *(const float4*)(pb + (yc1*NG + xc0)*NC);
            v11 = *(const float4*)(pb + (yc1*NG + xc1)*NC);
            const float* lb = ws + (size_t)3*PSZ + (size_t)p * LSZ + (size_t)j * (NG*NC) + lc;
            u0 = *(const float4*)(lb + zc0*NC);
            u1 = *(const float4*)(lb + zc1*NC);
        } else {
            const float* pb = praw[p] + ((size_t)j*NC + lc) * (NG*NG);
            const int o00 = yc0*NG + xc0, o01 = yc0*NG + xc1;
            const int o10 = yc1*NG + xc0, o11 = yc1*NG + xc1;
            v00 = make_float4(pb[o00], pb[NG*NG+o00], pb[2*NG*NG+o00], pb[3*NG*NG+o00]);
            v01 = make_float4(pb[o01], pb[NG*NG+o01], pb[2*NG*NG+o01], pb[3*NG*NG+o01]);
            v10 = make_float4(pb[o10], pb[NG*NG+o10], pb[2*NG*NG+o10], pb[3*NG*NG+o10]);
            v11 = make_float4(pb[o11], pb[NG*NG+o11], pb[2*NG*NG+o11], pb[3*NG*NG+o11]);
            const float* lb = lraw[p] + ((size_t)j*NC + lc) * NG;
            u0 = make_float4(lb[zc0], lb[NG+zc0], lb[2*NG+zc0], lb[3*NG+zc0]);
            u1 = make_float4(lb[zc1], lb[NG+zc1], lb[2*NG+zc1], lb[3*NG+zc1]);
        }

        float4 pf = make_float4(0.f, 0.f, 0.f, 0.f);
        pf = f4axpy(v00, mx0*my0, pf);
        pf = f4axpy(v01, mx1*my0, pf);
        pf = f4axpy(v10, mx0*my1, pf);
        pf = f4axpy(v11, mx1*my1, pf);

        float4 lf = make_float4(u0.x*mz0, u0.y*mz0, u0.z*mz0, u0.w*mz0);
        lf = f4axpy(u1, mz1, lf);

        sig.x = fmaf(pf.x, lf.x, sig.x);
        sig.y = fmaf(pf.y, lf.y, sig.y);
        sig.z = fmaf(pf.z, lf.z, sig.z);
        sig.w = fmaf(pf.w, lf.w, sig.w);
    }

    float s = (sig.x + sig.y) + (sig.z + sig.w);
    s += __shfl_xor(s, 1);
    s += __shfl_xor(s, 2);
    if ((tid & 3) == 0)
        out[(size_t)n * NJ + j] = fmaxf(s, 0.f);   // f32 output
}

// ---------------- launch ----------------

extern "C" void kernel_launch(void* const* d_in, const int* in_sizes, int n_in,
                              void* d_out, int out_size, void* d_ws, size_t ws_size,
                              hipStream_t stream) {
    // Identify inputs by flat element count (robust to ordering).
    const float* xyz = nullptr;
    const float* Tm  = nullptr;
    const float* P[3] = {nullptr, nullptr, nullptr};
    const float* L[3] = {nullptr, nullptr, nullptr};
    int pi = 0, li = 0;
    for (int i = 0; i < n_in; ++i) {
        const int s = in_sizes[i];
        if      (s == NPTS * 3)            xyz = (const float*)d_in[i];
        else if (s == 16 * NJ)             Tm  = (const float*)d_in[i];
        else if (s == NJ * NC * NG * NG) { if (pi < 3) P[pi++] = (const float*)d_in[i]; }
        else if (s == NJ * NC * NG)      { if (li < 3) L[li++] = (const float*)d_in[i]; }
    }
    if (!xyz || !Tm || pi != 3 || li != 3) {   // fallback: documented dict order
        xyz = (const float*)d_in[0];  Tm = (const float*)d_in[1];
        P[0] = (const float*)d_in[2]; P[1] = (const float*)d_in[3];
        P[2] = (const float*)d_in[4];
        L[0] = (const float*)d_in[5]; L[1] = (const float*)d_in[6];
        L[2] = (const float*)d_in[7];
    }
    float* out = (float*)d_out;
    float* ws  = (float*)d_ws;

    const size_t need = ((size_t)3 * PSZ + (size_t)3 * LSZ) * sizeof(float);
    const int nblocks = (NPTS * NJ * 4) / 256;   // 98304, exact

    if (ws_size >= need) {
        transpose_planes_k<<<dim3(NG*NG*NC/256, NJ, 3), 256, 0, stream>>>(P[0], P[1], P[2], ws);
        transpose_lines_k<<<dim3(LSZ/256, 1, 3), 256, 0, stream>>>(L[0], L[1], L[2], ws);
        trisample_k<true><<<nblocks, 256, 0, stream>>>(xyz, Tm, P[0], P[1], P[2],
                                                       L[0], L[1], L[2], ws, out);
    } else {
        trisample_k<false><<<nblocks, 256, 0, stream>>>(xyz, Tm, P[0], P[1], P[2],
                                                        L[0], L[1], L[2], ws, out);
    }
}

// Round 5
// 307.800 us; speedup vs baseline: 10.4633x; 1.2750x over previous
//
#include <hip/hip_runtime.h>
#include <hip/hip_fp16.h>

#define NPTS 262144
#define NJ   24
#define NC   16
#define NG   128
#define PSZ  (NJ*NG*NG*NC)   // halfs per transposed plane
#define LSZ  (NJ*NG*NC)      // halfs per transposed line set

typedef _Float16 h2 __attribute__((ext_vector_type(2)));
typedef _Float16 h8 __attribute__((ext_vector_type(8)));

static __device__ __forceinline__ h8 splat8(float w) {
    _Float16 h = (_Float16)w;
    return (h8){h,h,h,h,h,h,h,h};
}

// ---------------- transpose pre-passes: f32 [J][C][G][G] -> fp16 [J][G][G][C] ----------

__global__ __launch_bounds__(256) void transpose_planes_h(
    const float* __restrict__ p0, const float* __restrict__ p1,
    const float* __restrict__ p2, _Float16* __restrict__ ws)
{
    const int p = blockIdx.z, j = blockIdx.y;
    const int idx = blockIdx.x * 256 + threadIdx.x;  // [0, NG*NG*NC)
    const int c = idx & 15;
    const int x = (idx >> 4) & 127;
    const int y = idx >> 11;
    const float* src = (p == 0) ? p0 : (p == 1) ? p1 : p2;
    ws[(size_t)p * PSZ + (size_t)((j * NG + y) * NG + x) * NC + c] =
        (_Float16)src[((j * NC + c) * NG + y) * NG + x];
}

__global__ __launch_bounds__(256) void transpose_lines_h(
    const float* __restrict__ l0, const float* __restrict__ l1,
    const float* __restrict__ l2, _Float16* __restrict__ ws)
{
    const int p = blockIdx.z;
    const int idx = blockIdx.x * 256 + threadIdx.x;  // [0, NJ*NG*NC)
    const int c = idx & 15;
    const int z = (idx >> 4) & 127;
    const int j = idx >> 11;
    const float* src = (p == 0) ? l0 : (p == 1) ? l1 : l2;
    ws[(size_t)3 * PSZ + (size_t)p * LSZ + (size_t)(j * NG + z) * NC + c] =
        (_Float16)src[(j * NC + c) * NG + z];
}

// ---------------- main kernel: 2 lanes per (n,j) pair, 8 fp16 channels/lane ------------

__global__ __launch_bounds__(256) void trisample_h_k(
    const float* __restrict__ xyz, const float* __restrict__ Tm,
    const _Float16* __restrict__ wsP, const _Float16* __restrict__ wsL,
    float* __restrict__ out)
{
    const int tid  = blockIdx.x * 256 + threadIdx.x;
    const int pair = tid >> 1;          // j-major: pair = j*NPTS + n
    const int hh   = (tid & 1) << 3;    // channel offset 0 or 8
    const int j    = pair >> 18;        // NPTS = 2^18
    const int n    = pair & (NPTS - 1);

    const float px = xyz[3*n+0], py = xyz[3*n+1], pz = xyz[3*n+2];
    const float* Tj = Tm + 16*j;        // uniform within block -> scalar loads

    // Per-axis sampling state, computed ONCE per axis (reused by all 3 planes).
    // ix = ((pt+1.5)*(2/3)-1 + 1)*0.5*127 = pt*(127/3) + 63.5  (folded)
    float m0[3], m1[3];
    int   c0[3], c1[3];
#pragma unroll
    for (int a = 0; a < 3; ++a) {
        const float pt = fmaf(Tj[4*a+0], px,
                          fmaf(Tj[4*a+1], py,
                           fmaf(Tj[4*a+2], pz, Tj[4*a+3])));
        const float ia = fmaf(pt, 127.0f/3.0f, 63.5f);
        const float fa = floorf(ia);
        const int   i0 = (int)fa;
        const float w1 = ia - fa;
        m0[a] = (i0 >=  0 && i0 < NG    ) ? (1.0f - w1) : 0.0f;  // tap i0 validity
        m1[a] = (i0 >= -1 && i0 < NG - 1) ? w1          : 0.0f;  // tap i0+1 validity
        c0[a] = min(max(i0,     0), NG-1);
        c1[a] = min(max(i0 + 1, 0), NG-1);
    }

    const int M0[3] = {0,0,1}, M1[3] = {1,2,2}, MV[3] = {2,1,0};
    float sigma = 0.0f;
#pragma unroll
    for (int p = 0; p < 3; ++p) {
        const int A = M0[p], B = M1[p], V = MV[p];
        const _Float16* pb = wsP + (size_t)p * PSZ + (size_t)j * (NG*NG*NC) + hh;
        const _Float16* lb = wsL + (size_t)p * LSZ + (size_t)j * (NG*NC)   + hh;
        const int rb0 = c0[B] * (NG*NC), rb1 = c1[B] * (NG*NC);
        const int cb0 = c0[A] * NC,      cb1 = c1[A] * NC;

        const h8 v00 = *(const h8*)(pb + rb0 + cb0);   // 16B coalesced, 32B/record
        const h8 v01 = *(const h8*)(pb + rb0 + cb1);
        const h8 v10 = *(const h8*)(pb + rb1 + cb0);
        const h8 v11 = *(const h8*)(pb + rb1 + cb1);
        const h8 u0  = *(const h8*)(lb + c0[V] * NC);
        const h8 u1  = *(const h8*)(lb + c1[V] * NC);

        h8 pf = v00 * splat8(m0[A] * m0[B]);           // v_pk_fma_f16 x4 per tap
        pf += v01 * splat8(m1[A] * m0[B]);
        pf += v10 * splat8(m0[A] * m1[B]);
        pf += v11 * splat8(m1[A] * m1[B]);
        h8 lf = u0 * splat8(m0[V]);
        lf += u1 * splat8(m1[V]);

#if __has_builtin(__builtin_amdgcn_fdot2)
#pragma unroll
        for (int q = 0; q < 4; ++q) {                  // v_dot2_f32_f16, f32 accum
            const h2 a = {pf[2*q], pf[2*q+1]};
            const h2 b = {lf[2*q], lf[2*q+1]};
            sigma = __builtin_amdgcn_fdot2(a, b, sigma, false);
        }
#else
#pragma unroll
        for (int q = 0; q < 8; ++q)
            sigma += (float)pf[q] * (float)lf[q];
#endif
    }

    sigma += __shfl_xor(sigma, 1);      // combine ch0-7 + ch8-15
    if (hh == 0)
        out[(size_t)n * NJ + j] = fmaxf(sigma, 0.0f);
}

// ---------------- fallback (ws too small): round-3 scalar kernel, known-correct --------

__global__ __launch_bounds__(256) void simple_trisample_k(
    const float* __restrict__ xyz, const float* __restrict__ Tm,
    const float* __restrict__ p0, const float* __restrict__ p1,
    const float* __restrict__ p2, const float* __restrict__ l0,
    const float* __restrict__ l1, const float* __restrict__ l2,
    float* __restrict__ out)
{
    const int tid = blockIdx.x * 256 + threadIdx.x;
    const int j = tid >> 18;
    const int n = tid & (NPTS - 1);
    const float x = xyz[3*n+0], y = xyz[3*n+1], z = xyz[3*n+2];
    const float* Tj = Tm + 16*j;
    float g[3];
#pragma unroll
    for (int a = 0; a < 3; ++a) {
        const float pt = Tj[4*a+0]*x + Tj[4*a+1]*y + Tj[4*a+2]*z + Tj[4*a+3];
        g[a] = (pt + 1.5f) * (2.0f/3.0f) - 1.0f;
    }
    const float* P[3] = {p0, p1, p2};
    const float* L[3] = {l0, l1, l2};
    const int M0[3] = {0,0,1}, M1[3] = {1,2,2}, MV[3] = {2,1,0};
    float sigma = 0.0f;
#pragma unroll
    for (int p = 0; p < 3; ++p) {
        const float ix = (g[M0[p]] + 1.0f) * 63.5f;
        const float iy = (g[M1[p]] + 1.0f) * 63.5f;
        const float iz = (g[MV[p]] + 1.0f) * 63.5f;
        const float fx = floorf(ix), fy = floorf(iy), fz = floorf(iz);
        const int x0 = (int)fx, y0 = (int)fy, z0 = (int)fz;
        const float wx1 = ix - fx, wy1 = iy - fy, wz1 = iz - fz;
        const float mx0 = (x0   >= 0 && x0   < NG) ? (1.0f - wx1) : 0.0f;
        const float mx1 = (x0+1 >= 0 && x0+1 < NG) ? wx1 : 0.0f;
        const float my0 = (y0   >= 0 && y0   < NG) ? (1.0f - wy1) : 0.0f;
        const float my1 = (y0+1 >= 0 && y0+1 < NG) ? wy1 : 0.0f;
        const float mz0 = (z0   >= 0 && z0   < NG) ? (1.0f - wz1) : 0.0f;
        const float mz1 = (z0+1 >= 0 && z0+1 < NG) ? wz1 : 0.0f;
        const int xc0 = min(max(x0,0),NG-1), xc1 = min(max(x0+1,0),NG-1);
        const int yc0 = min(max(y0,0),NG-1), yc1 = min(max(y0+1,0),NG-1);
        const int zc0 = min(max(z0,0),NG-1), zc1 = min(max(z0+1,0),NG-1);
        const float w00 = mx0*my0, w01 = mx1*my0, w10 = mx0*my1, w11 = mx1*my1;
        const int o00 = yc0*NG+xc0, o01 = yc0*NG+xc1, o10 = yc1*NG+xc0, o11 = yc1*NG+xc1;
        const float* pb = P[p] + (size_t)j * NC * NG * NG;
        const float* lb = L[p] + (size_t)j * NC * NG;
#pragma unroll 4
        for (int c = 0; c < NC; ++c) {
            const float* pc = pb + (size_t)c * NG * NG;
            const float pf = pc[o00]*w00 + pc[o01]*w01 + pc[o10]*w10 + pc[o11]*w11;
            const float* lc = lb + (size_t)c * NG;
            sigma += pf * (lc[zc0]*mz0 + lc[zc1]*mz1);
        }
    }
    out[(size_t)n * NJ + j] = fmaxf(sigma, 0.0f);
}

// ---------------- launch ----------------

extern "C" void kernel_launch(void* const* d_in, const int* in_sizes, int n_in,
                              void* d_out, int out_size, void* d_ws, size_t ws_size,
                              hipStream_t stream) {
    const float* xyz = nullptr;
    const float* Tm  = nullptr;
    const float* P[3] = {nullptr, nullptr, nullptr};
    const float* L[3] = {nullptr, nullptr, nullptr};
    int pi = 0, li = 0;
    for (int i = 0; i < n_in; ++i) {
        const int s = in_sizes[i];
        if      (s == NPTS * 3)            xyz = (const float*)d_in[i];
        else if (s == 16 * NJ)             Tm  = (const float*)d_in[i];
        else if (s == NJ * NC * NG * NG) { if (pi < 3) P[pi++] = (const float*)d_in[i]; }
        else if (s == NJ * NC * NG)      { if (li < 3) L[li++] = (const float*)d_in[i]; }
    }
    if (!xyz || !Tm || pi != 3 || li != 3) {
        xyz = (const float*)d_in[0];  Tm = (const float*)d_in[1];
        P[0] = (const float*)d_in[2]; P[1] = (const float*)d_in[3];
        P[2] = (const float*)d_in[4];
        L[0] = (const float*)d_in[5]; L[1] = (const float*)d_in[6];
        L[2] = (const float*)d_in[7];
    }
    float* out = (float*)d_out;
    _Float16* ws = (_Float16*)d_ws;

    const size_t need = ((size_t)3 * PSZ + (size_t)3 * LSZ) * sizeof(_Float16);  // ~38 MB

    if (ws_size >= need) {
        transpose_planes_h<<<dim3(NG*NG*NC/256, NJ, 3), 256, 0, stream>>>(P[0], P[1], P[2], ws);
        transpose_lines_h<<<dim3(LSZ/256, 1, 3), 256, 0, stream>>>(L[0], L[1], L[2], ws);
        const int nblocks = (NPTS * NJ * 2) / 256;   // 49152, exact
        trisample_h_k<<<nblocks, 256, 0, stream>>>(xyz, Tm, ws, ws + (size_t)3*PSZ, out);
    } else {
        simple_trisample_k<<<(NPTS*NJ)/256, 256, 0, stream>>>(xyz, Tm, P[0], P[1], P[2],
                                                              L[0], L[1], L[2], out);
    }
}